// Round 8
// baseline (386.875 us; speedup 1.0000x reference)
//
#include <hip/hip_runtime.h>

typedef float4 f4;

// ---- ws float-offset layout ----
#define F_S0    0        // 64: per-channel W0 scale
#define F_BN0   64       // g[64] be[64] m[64] r[64]
#define F_BN1   320
#define F_BN2   576
#define F_BN3   832      // 256 floats (c<10 valid, rest 0)
#define F_WQ1   1088     // [16][64][4] fp32
#define F_WQ2   5184     // [16][64][4]
#define F_WQ3   9280     // [16][64][4] (zeros for c>=10)
#define F_WI0   13376    // int8 W0 tiled [768][64][4] = 196608 B
#define F_WQ0   62528    // fp32 W0 tiled [768][64][4] = 196608 floats
#define WS_NEED_F32 ((size_t)(F_WQ0 + 196608) * 4)

struct InPtrs { const float* p[25]; };

// ---------------- prep: fp32 scales/weights/BN consts (np-f32 exact ops) ----------------
__global__ __launch_bounds__(256) void qtfc_prep(InPtrs P, float* __restrict__ wsf, int wf32) {
#pragma clang fp contract(off)
  __shared__ float red[256];
  const int tid = threadIdx.x, b = blockIdx.x;
  if (b < 64) {
    const int c = b;                       // output channel
    const float* W = P.p[1];
    float mx = 0.f;
    for (int k = tid; k < 3072; k += 256) mx = fmaxf(mx, fabsf(W[c * 3072 + k]));
    red[tid] = mx; __syncthreads();
    for (int s = 128; s > 0; s >>= 1) { if (tid < s) red[tid] = fmaxf(red[tid], red[tid + s]); __syncthreads(); }
    const float sv = fmaxf(__fdiv_rn(red[0], 7.f), 1e-8f);
    signed char* wi = (signed char*)(wsf + F_WI0);
    for (int k = tid; k < 3072; k += 256) {
      const float r = rintf(__fdiv_rn(W[c * 3072 + k], sv));
      const int idx = (k >> 2) * 256 + c * 4 + (k & 3);   // [chunk][lane=c][4]
      wi[idx] = (signed char)(int)r;
      if (wf32) wsf[F_WQ0 + idx] = __fmul_rn(r, sv);
    }
    if (tid == 0) {
      wsf[F_S0 + c] = sv;
      const float gg = P.p[3][c], be = P.p[4][c], m = P.p[5][c], v = P.p[6][c];
      const float rr = __fdiv_rn(1.f, __fsqrt_rn(__fadd_rn(v, 1e-5f)));
      wsf[F_BN0 + c] = gg; wsf[F_BN0 + 64 + c] = be; wsf[F_BN0 + 128 + c] = m; wsf[F_BN0 + 192 + c] = rr;
    }
  } else if (b < 192) {
    const int lay = b >> 6, c = b & 63;    // lay = 1,2
    const float* W = P.p[1 + 6 * lay];
    red[tid] = (tid < 64) ? fabsf(W[c * 64 + tid]) : 0.f; __syncthreads();
    for (int s = 128; s > 0; s >>= 1) { if (tid < s) red[tid] = fmaxf(red[tid], red[tid + s]); __syncthreads(); }
    const float sv = fmaxf(__fdiv_rn(red[0], 7.f), 1e-8f);
    float* wq = wsf + (lay == 1 ? F_WQ1 : F_WQ2);
    if (tid < 64) {
      const int k = tid;
      wq[(k >> 2) * 256 + c * 4 + (k & 3)] = __fmul_rn(rintf(__fdiv_rn(W[c * 64 + k], sv)), sv);
    }
    if (tid == 0) {
      const int base = (lay == 1) ? F_BN1 : F_BN2;
      const float gg = P.p[3 + 6 * lay][c], be = P.p[4 + 6 * lay][c];
      const float m = P.p[5 + 6 * lay][c], v = P.p[6 + 6 * lay][c];
      const float rr = __fdiv_rn(1.f, __fsqrt_rn(__fadd_rn(v, 1e-5f)));
      wsf[base + c] = gg; wsf[base + 64 + c] = be; wsf[base + 128 + c] = m; wsf[base + 192 + c] = rr;
    }
  } else {
    // W3: zero-pad then per-tensor quant over 10x64
    for (int i = tid; i < 4096; i += 256) wsf[F_WQ3 + i] = 0.f;
    for (int i = tid; i < 256; i += 256) wsf[F_BN3 + i] = 0.f;
    __syncthreads();
    const float* W = P.p[19];
    float mx = 0.f;
    for (int k = tid; k < 640; k += 256) mx = fmaxf(mx, fabsf(W[k]));
    red[tid] = mx; __syncthreads();
    for (int s = 128; s > 0; s >>= 1) { if (tid < s) red[tid] = fmaxf(red[tid], red[tid + s]); __syncthreads(); }
    const float sv = fmaxf(__fdiv_rn(red[0], 7.f), 1e-8f);
    for (int i = tid; i < 640; i += 256) {
      const int c = i >> 6, k = i & 63;
      wsf[F_WQ3 + (k >> 2) * 256 + c * 4 + (k & 3)] = __fmul_rn(rintf(__fdiv_rn(W[i], sv)), sv);
    }
    if (tid < 10) {
      const float gg = P.p[21][tid], be = P.p[22][tid], m = P.p[23][tid], v = P.p[24][tid];
      const float rr = __fdiv_rn(1.f, __fsqrt_rn(__fadd_rn(v, 1e-5f)));
      wsf[F_BN3 + tid] = gg; wsf[F_BN3 + 16 + tid] = be; wsf[F_BN3 + 32 + tid] = m; wsf[F_BN3 + 48 + tid] = rr;
    }
  }
}

// ---------------- exact-np helpers ----------------
__device__ __forceinline__ float bn_act4(float hv, float g, float be, float m, float r) {
#pragma clang fp contract(off)
  const float bnv = __fadd_rn(__fmul_rn(__fmul_rn(g, __fsub_rn(hv, m)), r), be);
  const float y = fminf(fmaxf(bnv, -1.f), 1.f);
  return __fdiv_rn(rintf(__fmul_rn(y, 7.f)), 7.f);
}
__device__ __forceinline__ float lutq(float v, const float* lut) {
#pragma clang fp contract(off)
  const float y = fminf(fmaxf(v, -1.f), 1.f);
  const float r = rintf(__fmul_rn(y, 127.f));
  return lut[(int)r + 127];   // == __fdiv_rn(r, 127.f)
}
__device__ __forceinline__ f4 q4(f4 v, const float* lut) {
  f4 q; q.x = lutq(v.x, lut); q.y = lutq(v.y, lut); q.z = lutq(v.z, lut); q.w = lutq(v.w, lut);
  return q;
}
__device__ __forceinline__ f4 dec8(int d, float sv) {
#pragma clang fp contract(off)
  f4 w;
  w.x = __fmul_rn((float)((signed char)(d & 255)), sv);
  w.y = __fmul_rn((float)((signed char)((d >> 8) & 255)), sv);
  w.z = __fmul_rn((float)((signed char)((d >> 16) & 255)), sv);
  w.w = __fmul_rn((float)((signed char)((d >> 24) & 255)), sv);
  return w;
}

// ---------------- main: lane = (row-half, ch-pair), wave = 16 rows, no barriers ----------------
template<int W8>
__global__ __launch_bounds__(256) void qtfc_main(const float* __restrict__ x,
                                                 const float* __restrict__ wsf,
                                                 float* __restrict__ out) {
#pragma clang fp contract(off)
  __shared__ __align__(16) float smem[4][2304];  // per wave: xt dbuf [2][256]f4 | lut [2048:2304)
  const int tid = threadIdx.x, w = tid >> 6, l = tid & 63;
  float* R = smem[w];
  f4* xt4 = (f4*)R;
  float* lut = R + 2048;
  const int row0 = blockIdx.x * 64 + w * 16;

#pragma unroll
  for (int ii = 0; ii < 4; ++ii) {
    const int idx = ii * 64 + l;
    lut[idx] = __fdiv_rn((float)(idx - 127), 127.f);
  }

  const int c_lo = l & 31;          // this lane's low channel; high = c_lo+32
  const int rh = l >> 5;            // row half: rows rh*8 .. rh*8+7

  float svL = 0.f, svH = 0.f;
  if (W8) { svL = wsf[F_S0 + c_lo]; svH = wsf[F_S0 + c_lo + 32]; }

  // x staging: lane covers row = l&15, k-slots (l>>4)+4i within 64-k tile
  const int rowl = l & 15, sb = l >> 4, key = rowl & 7;
  const float* xb = x + (long)(row0 + rowl) * 3072 + sb * 4;
  const int stw0 = rowl * 16 + ((sb) ^ key);
  const int stw1 = rowl * 16 + ((sb + 4) ^ key);
  const int stw2 = rowl * 16 + ((sb + 8) ^ key);
  const int stw3 = rowl * 16 + ((sb + 12) ^ key);

  float accL[8], accH[8], hsL[8], hsH[8];
#pragma unroll
  for (int r = 0; r < 8; ++r) { accL[r] = 0.f; accH[r] = 0.f; hsL[r] = 0.f; hsH[r] = 0.f; }

  const f4* wq0 = (const f4*)(wsf + F_WQ0);
  const int* wi0 = (const int*)(wsf + F_WI0);

  // prologue: stage tile 0 into buf0, prefetch tile 1 x
  f4 gx0 = *(const f4*)(xb);
  f4 gx1 = *(const f4*)(xb + 16);
  f4 gx2 = *(const f4*)(xb + 32);
  f4 gx3 = *(const f4*)(xb + 48);
  xt4[stw0] = q4(gx0, lut); xt4[stw1] = q4(gx1, lut);
  xt4[stw2] = q4(gx2, lut); xt4[stw3] = q4(gx3, lut);
  gx0 = *(const f4*)(xb + 64);
  gx1 = *(const f4*)(xb + 80);
  gx2 = *(const f4*)(xb + 96);
  gx3 = *(const f4*)(xb + 112);

  f4 wAL[4], wAH[4], wBL[4], wBH[4];

#define LDW(WL, WH, G0)                                            \
  {                                                                \
    const int _g = (G0);                                           \
    if (!W8) {                                                     \
      _Pragma("unroll")                                            \
      for (int cc4 = 0; cc4 < 4; ++cc4) {                          \
        WL[cc4] = wq0[(_g + cc4) * 64 + c_lo];                     \
        WH[cc4] = wq0[(_g + cc4) * 64 + c_lo + 32];                \
      }                                                            \
    } else {                                                       \
      _Pragma("unroll")                                            \
      for (int cc4 = 0; cc4 < 4; ++cc4) {                          \
        WL[cc4] = dec8(wi0[(_g + cc4) * 64 + c_lo], svL);          \
        WH[cc4] = dec8(wi0[(_g + cc4) * 64 + c_lo + 32], svH);     \
      }                                                            \
    }                                                              \
  }

#define FMAG(WL, WH, C0, XW)                                       \
  {                                                                \
    _Pragma("unroll")                                              \
    for (int cc4 = 0; cc4 < 4; ++cc4) {                            \
      const int c = (C0) + cc4;                                    \
      const f4 wl = WL[cc4], wh = WH[cc4];                         \
      _Pragma("unroll")                                            \
      for (int r8 = 0; r8 < 8; ++r8) {                             \
        const f4 xv = (XW)[r8 * 16 + (c ^ r8)];                    \
        float aL = accL[r8], aH = accH[r8];                        \
        aL = __fmaf_rn(xv.x, wl.x, aL); aH = __fmaf_rn(xv.x, wh.x, aH); \
        aL = __fmaf_rn(xv.y, wl.y, aL); aH = __fmaf_rn(xv.y, wh.y, aH); \
        aL = __fmaf_rn(xv.z, wl.z, aL); aH = __fmaf_rn(xv.z, wh.z, aH); \
        aL = __fmaf_rn(xv.w, wl.w, aL); aH = __fmaf_rn(xv.w, wh.w, aH); \
        accL[r8] = aL; accH[r8] = aH;                              \
      }                                                            \
    }                                                              \
  }

  LDW(wAL, wAH, 0);   // tile 0, group 0

#pragma unroll 1
  for (int t = 0; t < 48; ++t) {
    const int p = t & 1;
    const f4* xw = xt4 + p * 256 + rh * 128;
    const int g0 = t * 16;

    LDW(wBL, wBH, g0 + 4);
    FMAG(wAL, wAH, 0, xw);

    LDW(wAL, wAH, g0 + 8);
    if (t < 47) {   // stage tile t+1 into other buffer (overlaps with FMAs)
      f4* xo = xt4 + (p ^ 1) * 256;
      xo[stw0] = q4(gx0, lut); xo[stw1] = q4(gx1, lut);
      xo[stw2] = q4(gx2, lut); xo[stw3] = q4(gx3, lut);
    }
    FMAG(wBL, wBH, 4, xw);

    LDW(wBL, wBH, g0 + 12);
    {   // prefetch x for tile t+2
      const int tn = (t + 2 < 48) ? t + 2 : 47;
      gx0 = *(const f4*)(xb + tn * 64);
      gx1 = *(const f4*)(xb + tn * 64 + 16);
      gx2 = *(const f4*)(xb + tn * 64 + 32);
      gx3 = *(const f4*)(xb + tn * 64 + 48);
    }
    FMAG(wAL, wAH, 8, xw);

    LDW(wAL, wAH, (t < 47) ? (g0 + 16) : (g0 + 12));
    FMAG(wBL, wBH, 12, xw);

    if ((t % 6) == 5) {   // KC=384 boundary: sequential fp32 block-sum combine
#pragma unroll
      for (int r = 0; r < 8; ++r) {
        hsL[r] = __fadd_rn(hsL[r], accL[r]); accL[r] = 0.f;
        hsH[r] = __fadd_rn(hsH[r], accH[r]); accH[r] = 0.f;
      }
    }
  }
#undef LDW
#undef FMAG

  float* xa1 = R;            // a1 [16][64] = buf0
  float* a2  = R + 1024;     // a2 = buf1

  // ---- layer-0 epilogue: BN + 4-bit act -> a1 ----
  {
    const float gL = wsf[F_BN0 + c_lo],       beL = wsf[F_BN0 + 64 + c_lo];
    const float mL = wsf[F_BN0 + 128 + c_lo], rL  = wsf[F_BN0 + 192 + c_lo];
    const float gH = wsf[F_BN0 + c_lo + 32],       beH = wsf[F_BN0 + 96 + c_lo];
    const float mH = wsf[F_BN0 + 160 + c_lo], rH  = wsf[F_BN0 + 224 + c_lo];
#pragma unroll
    for (int r8 = 0; r8 < 8; ++r8) {
      const int row = rh * 8 + r8;
      xa1[row * 64 + c_lo]      = bn_act4(hsL[r8], gL, beL, mL, rL);
      xa1[row * 64 + c_lo + 32] = bn_act4(hsH[r8], gH, beH, mH, rH);
    }
  }

  // ---- layer 1: a1 -> a2 (lane = channel l) ----
  {
    const f4* wq1 = (const f4*)(wsf + F_WQ1);
    const f4* a14 = (const f4*)xa1;
    float a1c[16];
#pragma unroll
    for (int r = 0; r < 16; ++r) a1c[r] = 0.f;
#pragma unroll
    for (int cc = 0; cc < 16; ++cc) {
      const f4 wf = wq1[cc * 64 + l];
#pragma unroll
      for (int r = 0; r < 16; ++r) {
        const f4 xv = a14[r * 16 + cc];
        float a = a1c[r];
        a = __fmaf_rn(xv.x, wf.x, a);
        a = __fmaf_rn(xv.y, wf.y, a);
        a = __fmaf_rn(xv.z, wf.z, a);
        a = __fmaf_rn(xv.w, wf.w, a);
        a1c[r] = a;
      }
    }
    const float g = wsf[F_BN1 + l], be = wsf[F_BN1 + 64 + l];
    const float m = wsf[F_BN1 + 128 + l], rr = wsf[F_BN1 + 192 + l];
#pragma unroll
    for (int r = 0; r < 16; ++r)
      a2[r * 64 + l] = bn_act4(a1c[r], g, be, m, rr);
  }

  // ---- layer 2: a2 -> a1 ----
  {
    const f4* wq2 = (const f4*)(wsf + F_WQ2);
    const f4* a24 = (const f4*)a2;
    float a2c[16];
#pragma unroll
    for (int r = 0; r < 16; ++r) a2c[r] = 0.f;
#pragma unroll
    for (int cc = 0; cc < 16; ++cc) {
      const f4 wf = wq2[cc * 64 + l];
#pragma unroll
      for (int r = 0; r < 16; ++r) {
        const f4 xv = a24[r * 16 + cc];
        float a = a2c[r];
        a = __fmaf_rn(xv.x, wf.x, a);
        a = __fmaf_rn(xv.y, wf.y, a);
        a = __fmaf_rn(xv.z, wf.z, a);
        a = __fmaf_rn(xv.w, wf.w, a);
        a2c[r] = a;
      }
    }
    const float g = wsf[F_BN2 + l], be = wsf[F_BN2 + 64 + l];
    const float m = wsf[F_BN2 + 128 + l], rr = wsf[F_BN2 + 192 + l];
#pragma unroll
    for (int r = 0; r < 16; ++r)
      xa1[r * 64 + l] = bn_act4(a2c[r], g, be, m, rr);
  }

  // ---- layer 3: 10 outputs, BN affine, no act ----
  {
    const f4* wq3 = (const f4*)(wsf + F_WQ3);
    const f4* a14 = (const f4*)xa1;
    float a3c[16];
#pragma unroll
    for (int r = 0; r < 16; ++r) a3c[r] = 0.f;
#pragma unroll
    for (int cc = 0; cc < 16; ++cc) {
      const f4 wf = wq3[cc * 64 + l];
#pragma unroll
      for (int r = 0; r < 16; ++r) {
        const f4 xv = a14[r * 16 + cc];
        float a = a3c[r];
        a = __fmaf_rn(xv.x, wf.x, a);
        a = __fmaf_rn(xv.y, wf.y, a);
        a = __fmaf_rn(xv.z, wf.z, a);
        a = __fmaf_rn(xv.w, wf.w, a);
        a3c[r] = a;
      }
    }
    if (l < 10) {
      const float g = wsf[F_BN3 + l], be = wsf[F_BN3 + 16 + l];
      const float m = wsf[F_BN3 + 32 + l], rr = wsf[F_BN3 + 48 + l];
#pragma unroll
      for (int r = 0; r < 16; ++r) {
        const float o = __fadd_rn(__fmul_rn(__fmul_rn(g, __fsub_rn(a3c[r], m)), rr), be);
        out[(long)(row0 + r) * 10 + l] = o;
      }
    }
  }
}

extern "C" void kernel_launch(void* const* d_in, const int* in_sizes, int n_in,
                              void* d_out, int out_size, void* d_ws, size_t ws_size,
                              hipStream_t stream) {
  (void)in_sizes; (void)n_in; (void)out_size;
  InPtrs P;
  for (int i = 0; i < 25; ++i) P.p[i] = (const float*)d_in[i];
  float* wsf = (float*)d_ws;
  const int wf32 = (ws_size >= WS_NEED_F32) ? 1 : 0;
  qtfc_prep<<<193, 256, 0, stream>>>(P, wsf, wf32);
  if (wf32)
    qtfc_main<0><<<512, 256, 0, stream>>>((const float*)d_in[0], wsf, (float*)d_out);
  else
    qtfc_main<1><<<512, 256, 0, stream>>>((const float*)d_in[0], wsf, (float*)d_out);
}

// Round 9
// 319.976 us; speedup vs baseline: 1.2091x; 1.2091x over previous
//
#include <hip/hip_runtime.h>

typedef float4 f4;

// ---- ws float-offset layout ----
#define F_S0    0        // 64: per-channel W0 scale
#define F_BN0   64       // g[64] be[64] m[64] r[64]
#define F_BN1   320
#define F_BN2   576
#define F_BN3   832      // 256 floats (c<10 valid, rest 0)
#define F_WQ1   1088     // [16][64][4] fp32
#define F_WQ2   5184     // [16][64][4]
#define F_WQ3   9280     // [16][64][4] (zeros for c>=10)
#define F_WI0   13376    // int8 W0 tiled [768][64][4] = 196608 B
#define F_WQ0   62528    // fp32 W0 tiled [768][64][4] = 196608 floats
#define WS_NEED_F32 ((size_t)(F_WQ0 + 196608) * 4)

struct InPtrs { const float* p[25]; };

// ---------------- prep: fp32 scales/weights/BN consts (np-f32 exact ops) ----------------
__global__ __launch_bounds__(256) void qtfc_prep(InPtrs P, float* __restrict__ wsf, int wf32) {
#pragma clang fp contract(off)
  __shared__ float red[256];
  const int tid = threadIdx.x, b = blockIdx.x;
  if (b < 64) {
    const int c = b;                       // output channel
    const float* W = P.p[1];
    float mx = 0.f;
    for (int k = tid; k < 3072; k += 256) mx = fmaxf(mx, fabsf(W[c * 3072 + k]));
    red[tid] = mx; __syncthreads();
    for (int s = 128; s > 0; s >>= 1) { if (tid < s) red[tid] = fmaxf(red[tid], red[tid + s]); __syncthreads(); }
    const float sv = fmaxf(__fdiv_rn(red[0], 7.f), 1e-8f);
    signed char* wi = (signed char*)(wsf + F_WI0);
    for (int k = tid; k < 3072; k += 256) {
      const float r = rintf(__fdiv_rn(W[c * 3072 + k], sv));
      const int idx = (k >> 2) * 256 + c * 4 + (k & 3);   // [chunk][lane=c][4]
      wi[idx] = (signed char)(int)r;
      if (wf32) wsf[F_WQ0 + idx] = __fmul_rn(r, sv);
    }
    if (tid == 0) {
      wsf[F_S0 + c] = sv;
      const float gg = P.p[3][c], be = P.p[4][c], m = P.p[5][c], v = P.p[6][c];
      const float rr = __fdiv_rn(1.f, __fsqrt_rn(__fadd_rn(v, 1e-5f)));
      wsf[F_BN0 + c] = gg; wsf[F_BN0 + 64 + c] = be; wsf[F_BN0 + 128 + c] = m; wsf[F_BN0 + 192 + c] = rr;
    }
  } else if (b < 192) {
    const int lay = b >> 6, c = b & 63;    // lay = 1,2
    const float* W = P.p[1 + 6 * lay];
    red[tid] = (tid < 64) ? fabsf(W[c * 64 + tid]) : 0.f; __syncthreads();
    for (int s = 128; s > 0; s >>= 1) { if (tid < s) red[tid] = fmaxf(red[tid], red[tid + s]); __syncthreads(); }
    const float sv = fmaxf(__fdiv_rn(red[0], 7.f), 1e-8f);
    float* wq = wsf + (lay == 1 ? F_WQ1 : F_WQ2);
    if (tid < 64) {
      const int k = tid;
      wq[(k >> 2) * 256 + c * 4 + (k & 3)] = __fmul_rn(rintf(__fdiv_rn(W[c * 64 + k], sv)), sv);
    }
    if (tid == 0) {
      const int base = (lay == 1) ? F_BN1 : F_BN2;
      const float gg = P.p[3 + 6 * lay][c], be = P.p[4 + 6 * lay][c];
      const float m = P.p[5 + 6 * lay][c], v = P.p[6 + 6 * lay][c];
      const float rr = __fdiv_rn(1.f, __fsqrt_rn(__fadd_rn(v, 1e-5f)));
      wsf[base + c] = gg; wsf[base + 64 + c] = be; wsf[base + 128 + c] = m; wsf[base + 192 + c] = rr;
    }
  } else {
    // W3: zero-pad then per-tensor quant over 10x64
    for (int i = tid; i < 4096; i += 256) wsf[F_WQ3 + i] = 0.f;
    for (int i = tid; i < 256; i += 256) wsf[F_BN3 + i] = 0.f;
    __syncthreads();
    const float* W = P.p[19];
    float mx = 0.f;
    for (int k = tid; k < 640; k += 256) mx = fmaxf(mx, fabsf(W[k]));
    red[tid] = mx; __syncthreads();
    for (int s = 128; s > 0; s >>= 1) { if (tid < s) red[tid] = fmaxf(red[tid], red[tid + s]); __syncthreads(); }
    const float sv = fmaxf(__fdiv_rn(red[0], 7.f), 1e-8f);
    for (int i = tid; i < 640; i += 256) {
      const int c = i >> 6, k = i & 63;
      wsf[F_WQ3 + (k >> 2) * 256 + c * 4 + (k & 3)] = __fmul_rn(rintf(__fdiv_rn(W[i], sv)), sv);
    }
    if (tid < 10) {
      const float gg = P.p[21][tid], be = P.p[22][tid], m = P.p[23][tid], v = P.p[24][tid];
      const float rr = __fdiv_rn(1.f, __fsqrt_rn(__fadd_rn(v, 1e-5f)));
      wsf[F_BN3 + tid] = gg; wsf[F_BN3 + 16 + tid] = be; wsf[F_BN3 + 32 + tid] = m; wsf[F_BN3 + 48 + tid] = rr;
    }
  }
}

// ---------------- exact-np helpers ----------------
__device__ __forceinline__ float bn_act4(float hv, float g, float be, float m, float r) {
#pragma clang fp contract(off)
  const float bnv = __fadd_rn(__fmul_rn(__fmul_rn(g, __fsub_rn(hv, m)), r), be);
  const float y = fminf(fmaxf(bnv, -1.f), 1.f);
  return __fdiv_rn(rintf(__fmul_rn(y, 7.f)), 7.f);
}
__device__ __forceinline__ float lutq(float v, const float* lut) {
#pragma clang fp contract(off)
  const float y = fminf(fmaxf(v, -1.f), 1.f);
  const float r = rintf(__fmul_rn(y, 127.f));
  return lut[(int)r + 127];   // == __fdiv_rn(r, 127.f)
}
__device__ __forceinline__ f4 q4(f4 v, const float* lut) {
  f4 q; q.x = lutq(v.x, lut); q.y = lutq(v.y, lut); q.z = lutq(v.z, lut); q.w = lutq(v.w, lut);
  return q;
}
__device__ __forceinline__ f4 dec8(int d, float sv) {
#pragma clang fp contract(off)
  f4 w;
  w.x = __fmul_rn((float)((signed char)(d & 255)), sv);
  w.y = __fmul_rn((float)((signed char)((d >> 8) & 255)), sv);
  w.z = __fmul_rn((float)((signed char)((d >> 16) & 255)), sv);
  w.w = __fmul_rn((float)((signed char)((d >> 24) & 255)), sv);
  return w;
}

// ---- main: 8 rows/wave, lane = (row-half rh, ch-pair c/c+32); 4 waves/block; no barriers ----
template<int W8>
__global__ __launch_bounds__(256) void qtfc_main(const float* __restrict__ x,
                                                 const float* __restrict__ wsf,
                                                 float* __restrict__ out) {
#pragma clang fp contract(off)
  __shared__ __align__(16) float smem[4][1280];  // per wave: x dbuf [2][128]f4 = [0:1024) | lut [1024:1280)
  const int tid = threadIdx.x, w = tid >> 6, l = tid & 63;
  float* R = smem[w];
  f4* xt4 = (f4*)R;
  float* lut = R + 1024;
  const int row0w = blockIdx.x * 32 + w * 8;     // wave's 8 rows

#pragma unroll
  for (int ii = 0; ii < 4; ++ii) {
    const int idx = ii * 64 + l;
    lut[idx] = __fdiv_rn((float)(idx - 127), 127.f);
  }

  const int c_lo = l & 31;          // low channel; high = c_lo+32
  const int rh = l >> 5;            // row half: rows rh*4 .. rh*4+3

  float svL = 0.f, svH = 0.f;
  if (W8) { svL = wsf[F_S0 + c_lo]; svH = wsf[F_S0 + c_lo + 32]; }

  // x staging: lane stages row = l>>3 (local 0..7), k-slots (l&7) and (l&7)+8
  const int rowl = l >> 3, sb = l & 7;
  const float* xb = x + (long)(row0w + rowl) * 3072 + sb * 4;
  const int stw0 = rowl * 16 + (sb ^ rowl);
  const int stw1 = rowl * 16 + ((sb + 8) ^ rowl);

  float accL[4], accH[4], hsL[4], hsH[4];
#pragma unroll
  for (int r = 0; r < 4; ++r) { accL[r] = 0.f; accH[r] = 0.f; hsL[r] = 0.f; hsH[r] = 0.f; }

  const f4* wq0 = (const f4*)(wsf + F_WQ0);
  const int* wi0 = (const int*)(wsf + F_WI0);

  // prologue: stage tile 0 into buf0; prefetch tile 1 x
  f4 gx0 = *(const f4*)(xb);
  f4 gx1 = *(const f4*)(xb + 32);
  xt4[stw0] = q4(gx0, lut);
  xt4[stw1] = q4(gx1, lut);
  gx0 = *(const f4*)(xb + 64);
  gx1 = *(const f4*)(xb + 96);

  f4 wAL[2], wAH[2], wBL[2], wBH[2];

#define LDW(WL, WH, G0)                                            \
  {                                                                \
    const int _g = (G0);                                           \
    if (!W8) {                                                     \
      _Pragma("unroll")                                            \
      for (int cc2 = 0; cc2 < 2; ++cc2) {                          \
        WL[cc2] = wq0[(_g + cc2) * 64 + c_lo];                     \
        WH[cc2] = wq0[(_g + cc2) * 64 + c_lo + 32];                \
      }                                                            \
    } else {                                                       \
      _Pragma("unroll")                                            \
      for (int cc2 = 0; cc2 < 2; ++cc2) {                          \
        WL[cc2] = dec8(wi0[(_g + cc2) * 64 + c_lo], svL);          \
        WH[cc2] = dec8(wi0[(_g + cc2) * 64 + c_lo + 32], svH);     \
      }                                                            \
    }                                                              \
  }

#define FMAG(WL, WH, C0, XW)                                       \
  {                                                                \
    _Pragma("unroll")                                              \
    for (int cc2 = 0; cc2 < 2; ++cc2) {                            \
      const int c = (C0) + cc2;                                    \
      const f4 wl = WL[cc2], wh = WH[cc2];                         \
      _Pragma("unroll")                                            \
      for (int r4 = 0; r4 < 4; ++r4) {                             \
        const int rr = rh * 4 + r4;                                \
        const f4 xv = (XW)[rr * 16 + (c ^ rr)];                    \
        float aL = accL[r4], aH = accH[r4];                        \
        aL = __fmaf_rn(xv.x, wl.x, aL); aH = __fmaf_rn(xv.x, wh.x, aH); \
        aL = __fmaf_rn(xv.y, wl.y, aL); aH = __fmaf_rn(xv.y, wh.y, aH); \
        aL = __fmaf_rn(xv.z, wl.z, aL); aH = __fmaf_rn(xv.z, wh.z, aH); \
        aL = __fmaf_rn(xv.w, wl.w, aL); aH = __fmaf_rn(xv.w, wh.w, aH); \
        accL[r4] = aL; accH[r4] = aH;                              \
      }                                                            \
    }                                                              \
  }

  LDW(wAL, wAH, 0);   // tile 0, cc group 0

#pragma unroll 1
  for (int t = 0; t < 48; ++t) {
    const int p = t & 1;
    const f4* xw = xt4 + p * 128;
    const int g0 = t * 16;

    LDW(wBL, wBH, g0 + 2);  FMAG(wAL, wAH, 0, xw);
    LDW(wAL, wAH, g0 + 4);  FMAG(wBL, wBH, 2, xw);
    LDW(wBL, wBH, g0 + 6);
    if (t < 47) {           // stage tile t+1 into other buffer (overlaps FMAs)
      f4* xo = xt4 + (p ^ 1) * 128;
      xo[stw0] = q4(gx0, lut);
      xo[stw1] = q4(gx1, lut);
    }
    FMAG(wAL, wAH, 4, xw);
    LDW(wAL, wAH, g0 + 8);  FMAG(wBL, wBH, 6, xw);
    LDW(wBL, wBH, g0 + 10);
    {                       // prefetch x for tile t+2
      const int tn = (t + 2 < 48) ? t + 2 : 47;
      gx0 = *(const f4*)(xb + tn * 64);
      gx1 = *(const f4*)(xb + tn * 64 + 32);
    }
    FMAG(wAL, wAH, 8, xw);
    LDW(wAL, wAH, g0 + 12); FMAG(wBL, wBH, 10, xw);
    LDW(wBL, wBH, g0 + 14); FMAG(wAL, wAH, 12, xw);
    LDW(wAL, wAH, (t < 47) ? (g0 + 16) : (g0 + 14));
    FMAG(wBL, wBH, 14, xw);

    if ((t % 6) == 5) {     // KC=384 boundary: sequential fp32 block-sum combine
#pragma unroll
      for (int r = 0; r < 4; ++r) {
        hsL[r] = __fadd_rn(hsL[r], accL[r]); accL[r] = 0.f;
        hsH[r] = __fadd_rn(hsH[r], accH[r]); accH[r] = 0.f;
      }
    }
  }
#undef LDW
#undef FMAG

  float* xa1 = R;            // a1 [8][64] floats = buf area
  float* a2  = R + 512;

  // ---- layer-0 epilogue: BN + 4-bit act -> a1 ----
  {
    const float gL = wsf[F_BN0 + c_lo],       beL = wsf[F_BN0 + 64 + c_lo];
    const float mL = wsf[F_BN0 + 128 + c_lo], rL  = wsf[F_BN0 + 192 + c_lo];
    const float gH = wsf[F_BN0 + 32 + c_lo],  beH = wsf[F_BN0 + 96 + c_lo];
    const float mH = wsf[F_BN0 + 160 + c_lo], rH  = wsf[F_BN0 + 224 + c_lo];
#pragma unroll
    for (int r4 = 0; r4 < 4; ++r4) {
      const int rr = rh * 4 + r4;
      xa1[rr * 64 + c_lo]      = bn_act4(hsL[r4], gL, beL, mL, rL);
      xa1[rr * 64 + c_lo + 32] = bn_act4(hsH[r4], gH, beH, mH, rH);
    }
  }

  // ---- layer 1: a1 -> a2 (lane = channel l, 8 rows) ----
  {
    const f4* wq1 = (const f4*)(wsf + F_WQ1);
    const f4* a14 = (const f4*)xa1;
    float a1c[8];
#pragma unroll
    for (int r = 0; r < 8; ++r) a1c[r] = 0.f;
#pragma unroll
    for (int cc = 0; cc < 16; ++cc) {
      const f4 wf = wq1[cc * 64 + l];
#pragma unroll
      for (int r = 0; r < 8; ++r) {
        const f4 xv = a14[r * 16 + cc];
        float a = a1c[r];
        a = __fmaf_rn(xv.x, wf.x, a);
        a = __fmaf_rn(xv.y, wf.y, a);
        a = __fmaf_rn(xv.z, wf.z, a);
        a = __fmaf_rn(xv.w, wf.w, a);
        a1c[r] = a;
      }
    }
    const float g = wsf[F_BN1 + l], be = wsf[F_BN1 + 64 + l];
    const float m = wsf[F_BN1 + 128 + l], rr = wsf[F_BN1 + 192 + l];
#pragma unroll
    for (int r = 0; r < 8; ++r)
      a2[r * 64 + l] = bn_act4(a1c[r], g, be, m, rr);
  }

  // ---- layer 2: a2 -> a1 ----
  {
    const f4* wq2 = (const f4*)(wsf + F_WQ2);
    const f4* a24 = (const f4*)a2;
    float a2c[8];
#pragma unroll
    for (int r = 0; r < 8; ++r) a2c[r] = 0.f;
#pragma unroll
    for (int cc = 0; cc < 16; ++cc) {
      const f4 wf = wq2[cc * 64 + l];
#pragma unroll
      for (int r = 0; r < 8; ++r) {
        const f4 xv = a24[r * 16 + cc];
        float a = a2c[r];
        a = __fmaf_rn(xv.x, wf.x, a);
        a = __fmaf_rn(xv.y, wf.y, a);
        a = __fmaf_rn(xv.z, wf.z, a);
        a = __fmaf_rn(xv.w, wf.w, a);
        a2c[r] = a;
      }
    }
    const float g = wsf[F_BN2 + l], be = wsf[F_BN2 + 64 + l];
    const float m = wsf[F_BN2 + 128 + l], rr = wsf[F_BN2 + 192 + l];
#pragma unroll
    for (int r = 0; r < 8; ++r)
      xa1[r * 64 + l] = bn_act4(a2c[r], g, be, m, rr);
  }

  // ---- layer 3: 10 outputs, BN affine, no act ----
  {
    const f4* wq3 = (const f4*)(wsf + F_WQ3);
    const f4* a14 = (const f4*)xa1;
    float a3c[8];
#pragma unroll
    for (int r = 0; r < 8; ++r) a3c[r] = 0.f;
#pragma unroll
    for (int cc = 0; cc < 16; ++cc) {
      const f4 wf = wq3[cc * 64 + l];
#pragma unroll
      for (int r = 0; r < 8; ++r) {
        const f4 xv = a14[r * 16 + cc];
        float a = a3c[r];
        a = __fmaf_rn(xv.x, wf.x, a);
        a = __fmaf_rn(xv.y, wf.y, a);
        a = __fmaf_rn(xv.z, wf.z, a);
        a = __fmaf_rn(xv.w, wf.w, a);
        a3c[r] = a;
      }
    }
    if (l < 10) {
      const float g = wsf[F_BN3 + l], be = wsf[F_BN3 + 16 + l];
      const float m = wsf[F_BN3 + 32 + l], rr = wsf[F_BN3 + 48 + l];
#pragma unroll
      for (int r = 0; r < 8; ++r) {
        const float o = __fadd_rn(__fmul_rn(__fmul_rn(g, __fsub_rn(a3c[r], m)), rr), be);
        out[(long)(row0w + r) * 10 + l] = o;
      }
    }
  }
}

extern "C" void kernel_launch(void* const* d_in, const int* in_sizes, int n_in,
                              void* d_out, int out_size, void* d_ws, size_t ws_size,
                              hipStream_t stream) {
  (void)in_sizes; (void)n_in; (void)out_size;
  InPtrs P;
  for (int i = 0; i < 25; ++i) P.p[i] = (const float*)d_in[i];
  float* wsf = (float*)d_ws;
  const int wf32 = (ws_size >= WS_NEED_F32) ? 1 : 0;
  qtfc_prep<<<193, 256, 0, stream>>>(P, wsf, wf32);
  if (wf32)
    qtfc_main<0><<<1024, 256, 0, stream>>>((const float*)d_in[0], wsf, (float*)d_out);
  else
    qtfc_main<1><<<1024, 256, 0, stream>>>((const float*)d_in[0], wsf, (float*)d_out);
}